// Round 6
// baseline (182.765 us; speedup 1.0000x reference)
//
#include <hip/hip_runtime.h>
#include <hip/hip_bf16.h>

// ---------------------------------------------------------------------------
// Problem constants
// ---------------------------------------------------------------------------
#define B_  2
#define N_  2048
#define D_  1024
#define H_  16
#define DH_ 64
#define BN_ROWS (B_ * N_)   // 4096
#define EPS_ 1e-5f
#define QKV_N 3072          // fused [Q | K | V] output width

typedef __attribute__((ext_vector_type(8))) short bf16x8_t;
typedef __attribute__((ext_vector_type(4))) float f32x4_t;

typedef const unsigned int __attribute__((address_space(1)))* gas_ptr;
typedef unsigned int __attribute__((address_space(3)))* las_ptr;

// async global->LDS, 16B per lane, dest = wave-uniform base + lane*16
__device__ __forceinline__ void async16(const unsigned short* g, unsigned short* l) {
    __builtin_amdgcn_global_load_lds((gas_ptr)g, (las_ptr)l, 16, 0, 0);
}

__device__ __forceinline__ unsigned short f2bf(float f) {
    unsigned int u = __float_as_uint(f);
    unsigned int r = u + 0x7FFFu + ((u >> 16) & 1u);   // round-to-nearest-even
    return (unsigned short)(r >> 16);
}

// pack two f32 -> bf16x2
__device__ __forceinline__ unsigned int pk2bf(float a, float b) {
    __hip_bfloat162 t = __float22bfloat162_rn(float2{a, b});
    return *(unsigned int*)&t;
}

// ---------------------------------------------------------------------------
// Kernel 1: fused dual LayerNorm + all-weight bf16 transposes (one dispatch).
// blocks [0,4096): LN rows. blocks [4096,8192): weight transpose tiles.
// ---------------------------------------------------------------------------
__global__ __launch_bounds__(256) void ln_wt_kernel(
    const float* __restrict__ x,
    const float* __restrict__ g1, const float* __restrict__ b1,
    const float* __restrict__ g2, const float* __restrict__ b2,
    const float* __restrict__ Wq, const float* __restrict__ Wkv,
    const float* __restrict__ Wo,
    unsigned short* __restrict__ xn, unsigned short* __restrict__ cn,
    unsigned short* __restrict__ wqkvT, unsigned short* __restrict__ woT) {
    const int bid = blockIdx.x;
    const int tid = threadIdx.x;

    if (bid < BN_ROWS) {
        // ---- LayerNorm path ----
        const int row = bid;
        const float4 v = ((const float4*)(x + (size_t)row * D_))[tid];

        float s  = v.x + v.y + v.z + v.w;
        float s2 = v.x * v.x + v.y * v.y + v.z * v.z + v.w * v.w;
        #pragma unroll
        for (int off = 32; off > 0; off >>= 1) {
            s  += __shfl_down(s,  off);
            s2 += __shfl_down(s2, off);
        }
        __shared__ float red[8];
        if ((tid & 63) == 0) { red[tid >> 6] = s; red[4 + (tid >> 6)] = s2; }
        __syncthreads();
        const float S  = red[0] + red[1] + red[2] + red[3];
        const float S2 = red[4] + red[5] + red[6] + red[7];
        const float mean = S * (1.0f / D_);
        const float var  = S2 * (1.0f / D_) - mean * mean;
        const float rstd = rsqrtf(var + EPS_);

        const float4 G1 = ((const float4*)g1)[tid];
        const float4 B1 = ((const float4*)b1)[tid];
        const float4 G2 = ((const float4*)g2)[tid];
        const float4 B2 = ((const float4*)b2)[tid];

        float nx[4] = { (v.x - mean) * rstd, (v.y - mean) * rstd,
                        (v.z - mean) * rstd, (v.w - mean) * rstd };
        ushort4 o1, o2;
        o1.x = f2bf(nx[0] * G1.x + B1.x); o1.y = f2bf(nx[1] * G1.y + B1.y);
        o1.z = f2bf(nx[2] * G1.z + B1.z); o1.w = f2bf(nx[3] * G1.w + B1.w);
        o2.x = f2bf(nx[0] * G2.x + B2.x); o2.y = f2bf(nx[1] * G2.y + B2.y);
        o2.z = f2bf(nx[2] * G2.z + B2.z); o2.w = f2bf(nx[3] * G2.w + B2.w);
        ((ushort4*)(xn + (size_t)row * D_))[tid] = o1;
        ((ushort4*)(cn + (size_t)row * D_))[tid] = o2;
    } else {
        // ---- weight transpose path: fp32 [K=1024][N] -> bf16 [N][1024] ----
        const int zz = bid - BN_ROWS;           // 0..4095
        const float* src;
        unsigned short* dst;
        int N, t;
        if (zz < 1024)      { src = Wq;  dst = wqkvT;                       N = 1024; t = zz; }
        else if (zz < 3072) { src = Wkv; dst = wqkvT + (size_t)1024 * 1024; N = 2048; t = zz - 1024; }
        else                { src = Wo;  dst = woT;                         N = 1024; t = zz - 3072; }
        const int nb = N / 32;
        const int n0 = (t % nb) * 32, k0 = (t / nb) * 32;

        __shared__ float tile[32][33];
        const int tx = tid & 31, ty = tid >> 5;   // 32 x 8
        #pragma unroll
        for (int i = 0; i < 4; i++)
            tile[ty + i * 8][tx] = src[(size_t)(k0 + ty + i * 8) * N + n0 + tx];
        __syncthreads();
        #pragma unroll
        for (int i = 0; i < 4; i++)
            dst[(size_t)(n0 + ty + i * 8) * 1024 + k0 + tx] = f2bf(tile[tx][ty + i * 8]);
    }
}

// ---------------------------------------------------------------------------
// Kernel 2: bf16 GEMM (m97 structure), templated on BM (128 or 64) and
// min blocks/CU. async global->LDS (16B) staging, XOR swizzle on the GLOBAL
// source address -> conflict-free ds_read_b128. 4 waves in 2x2.
// FUSED (QKV): A = A0 (Q, pre-scaled 0.125*log2e) for cols<1024 else A1 (KV);
//   V region (cols>=2048) written TRANSPOSED-TILED to vt.
// ---------------------------------------------------------------------------
template <int BM, bool FUSED, bool BF16OUT, int MINW>
__global__ __launch_bounds__(256, MINW) void gemm_kernel(
    const unsigned short* __restrict__ A0, const unsigned short* __restrict__ A1,
    const unsigned short* __restrict__ Bt, void* __restrict__ Cv,
    unsigned short* __restrict__ vt, int M, int N, int K) {
    constexpr int WM = BM / 2, MT = WM / 16, AI = BM / 32;
    __shared__ unsigned short As[BM * 64];
    __shared__ unsigned short Bs[128 * 64];
    const int tid = threadIdx.x, lane = tid & 63, w = tid >> 6;
    const int quad = lane >> 4, l16 = lane & 15;
    const int lr8 = lane >> 3, pg8 = lane & 7;
    const int wr = (w >> 1) * WM, wc = (w & 1) * 64;
    const int bm = blockIdx.y * BM, bn = blockIdx.x * 128;
    const unsigned short* A = (FUSED && bn >= 1024) ? A1 : A0;
    const float cscale = (FUSED && bn < 1024) ? 0.180336880111120f : 1.0f;

    f32x4_t acc[MT][4] = {};
    for (int k0 = 0; k0 < K; k0 += 64) {
        #pragma unroll
        for (int i = 0; i < AI; i++) {
            const int rb = w * (BM / 4) + i * 8;
            const int r  = rb + lr8;
            const int g  = pg8 ^ (r & 7);
            async16(&A[(size_t)(bm + r) * K + k0 + g * 8], &As[rb * 64]);
        }
        #pragma unroll
        for (int i = 0; i < 4; i++) {
            const int rb = w * 32 + i * 8;
            const int r  = rb + lr8;
            const int g  = pg8 ^ (r & 7);
            async16(&Bt[(size_t)(bn + r) * K + k0 + g * 8], &Bs[rb * 64]);
        }
        __syncthreads();
        #pragma unroll
        for (int kk = 0; kk < 64; kk += 32) {
            bf16x8_t af[MT], bfr[4];
            const int g0 = (kk >> 3) + quad;
            #pragma unroll
            for (int t = 0; t < MT; t++)
                af[t] = *(const bf16x8_t*)&As[(wr + t * 16 + l16) * 64 +
                                              ((g0 ^ (l16 & 7)) * 8)];
            #pragma unroll
            for (int t = 0; t < 4; t++)
                bfr[t] = *(const bf16x8_t*)&Bs[(wc + t * 16 + l16) * 64 +
                                               ((g0 ^ (l16 & 7)) * 8)];
            #pragma unroll
            for (int mt = 0; mt < MT; mt++)
                #pragma unroll
                for (int nt = 0; nt < 4; nt++)
                    acc[mt][nt] = __builtin_amdgcn_mfma_f32_16x16x32_bf16(
                        af[mt], bfr[nt], acc[mt][nt], 0, 0, 0);
        }
        __syncthreads();
    }

    if (FUSED && bn >= 2048) {
        // V region -> tiled transpose into vt. Wave tile = 64 seq x 64 cols.
        const int seq0 = bm + wr;                 // multiple of 64
        const int bq = seq0 >> 11;                // batch
        const int kt = (seq0 & (N_ - 1)) >> 6;    // 64-key tile within batch
        #pragma unroll
        for (int nt = 0; nt < 4; nt++) {
            const int c = (bn - 2048) + wc + nt * 16 + l16;   // 0..1023
            unsigned short* dst =
                vt + (((size_t)(bq * 32 + kt) * 1024) + c) * 64;
            #pragma unroll
            for (int mt = 0; mt < 4; mt++) {
                uint2 v2 = { pk2bf(acc[mt][nt][0], acc[mt][nt][1]),
                             pk2bf(acc[mt][nt][2], acc[mt][nt][3]) };
                *(uint2*)&dst[mt * 16 + quad * 4] = v2;   // 4 consecutive keys
            }
        }
        return;
    }

    #pragma unroll
    for (int mt = 0; mt < MT; mt++)
        #pragma unroll
        for (int nt = 0; nt < 4; nt++)
            #pragma unroll
            for (int r = 0; r < 4; r++) {
                const int row = bm + wr + mt * 16 + quad * 4 + r;
                const int col = bn + wc + nt * 16 + l16;
                if (BF16OUT)
                    ((unsigned short*)Cv)[(size_t)row * N + col] =
                        f2bf(acc[mt][nt][r] * cscale);
                else
                    ((float*)Cv)[(size_t)row * N + col] = acc[mt][nt][r];
            }
}

// ---------------------------------------------------------------------------
// Kernel 3: causal flash attention, S^T scheme, double-buffered K/V.
// 1024 single-64q-tile blocks, 3 blocks/CU (LDS 50K), LPT dispatch order
// (qt=31 first -> long blocks start first, short ones backfill), XCD-local
// bh in low bits (XCD = bid%8 independent of qt). One barrier per iter;
// prefetch issued right after it has a full compute phase to land.
// ---------------------------------------------------------------------------
__global__ __launch_bounds__(256, 3) void flash_attn_kernel(
    const unsigned short* __restrict__ qkv, const unsigned short* __restrict__ vt,
    unsigned short* __restrict__ out) {
    __shared__ unsigned short Qs[64 * 64];       // [query][dh], swizzled
    __shared__ unsigned short Ks[2][64 * 64];    // [key][dh], swizzled, dbuf
    __shared__ unsigned short Vts[2][64 * 64];   // [dh][key], swizzled, dbuf
    __shared__ unsigned short Ps[4][16 * 72];    // wave-private [query][key]

    const int tid = threadIdx.x, lane = tid & 63, w = tid >> 6;
    const int quad = lane >> 4, l16 = lane & 15;
    const int lr8 = lane >> 3, pg8 = lane & 7;
    // LPT + XCD-local decode: qt descends with bid; bh pinned to XCD bid%8
    const int bid = blockIdx.x;
    const int b5  = bid & 31;
    const int bh  = (b5 & 7) * 4 + (b5 >> 3);    // 0..31, XCD-local groups
    const int qt  = 31 - (bid >> 5);             // 31 first (LPT)
    const int b = bh >> 4, h = bh & 15;
    const int qs = qt * 64;
    const int niter = qt + 1;

    const unsigned short* qb  = qkv + (size_t)(b * N_) * QKV_N + h * DH_;
    const unsigned short* kb  = qb + 1024;
    const unsigned short* vtb = vt + ((size_t)(b * 32) * 1024 + h * 64) * 64;

    bf16x8_t ones;
    #pragma unroll
    for (int j = 0; j < 8; j++) ones[j] = (short)0x3F80;   // bf16 1.0

    // per-lane staging source offsets (strength-reduced in the loop)
    const int r0 = w * 16 + lr8;           // i=0 row
    const int r1 = r0 + 8;                 // i=1 row
    const int g0s = pg8 ^ (r0 & 7);
    const int g1s = pg8 ^ (r1 & 7);
    const unsigned short* kp0 = &kb[(size_t)r0 * QKV_N + g0s * 8];
    const unsigned short* kp1 = &kb[(size_t)r1 * QKV_N + g1s * 8];
    const unsigned short* vp0 = &vtb[(size_t)r0 * 64 + g0s * 8];
    const unsigned short* vp1 = &vtb[(size_t)r1 * 64 + g1s * 8];
    const int rb0 = w * 16, rb1 = w * 16 + 8;

    // stage Q + K0 + V0
    async16(&qb[(size_t)(qs + r0) * QKV_N + g0s * 8], &Qs[rb0 * 64]);
    async16(&qb[(size_t)(qs + r1) * QKV_N + g1s * 8], &Qs[rb1 * 64]);
    async16(kp0, &Ks[0][rb0 * 64]);
    async16(kp1, &Ks[0][rb1 * 64]);
    async16(vp0, &Vts[0][rb0 * 64]);
    async16(vp1, &Vts[0][rb1 * 64]);
    __syncthreads();

    // hoisted Q B-fragments (Qs dead afterwards)
    bf16x8_t qf[2];
    #pragma unroll
    for (int k2 = 0; k2 < 2; k2++) {
        const int gq = k2 * 4 + quad;
        qf[k2] = *(const bf16x8_t*)&Qs[(w * 16 + l16) * 64 + ((gq ^ (l16 & 7)) * 8)];
    }

    // invariant LDS read offsets
    int ksoff[2][4], vtoff[2][4], psoff[2];
    #pragma unroll
    for (int k2 = 0; k2 < 2; k2++) {
        const int gq = k2 * 4 + quad;
        #pragma unroll
        for (int t = 0; t < 4; t++) {
            ksoff[k2][t] = (t * 16 + l16) * 64 + ((gq ^ (l16 & 7)) * 8);
            vtoff[k2][t] = ksoff[k2][t];
        }
        psoff[k2] = l16 * 72 + k2 * 32 + quad * 8;
    }
    const int qy = qs + w * 16 + l16;      // this lane's query (for masking)

    f32x4_t o[4] = {};
    f32x4_t lacc = {};

    for (int jt = 0; jt < niter; jt++) {
        if (jt) __syncthreads();   // ends compute jt-1; drains stage of buf jt&1

        // prefetch next K/V tile into the other buffer
        if (jt + 1 < niter) {
            const size_t koff = (size_t)(jt + 1) * 64 * QKV_N;
            const size_t voff = (size_t)(jt + 1) * 1024 * 64;
            const int bsel = (jt + 1) & 1;
            async16(kp0 + koff, &Ks[bsel][rb0 * 64]);
            async16(kp1 + koff, &Ks[bsel][rb1 * 64]);
            async16(vp0 + voff, &Vts[bsel][rb0 * 64]);
            async16(vp1 + voff, &Vts[bsel][rb1 * 64]);
        }
        const int buf = jt & 1;
        const int js = jt * 64;

        // S^T = K . Q^T : m = 64 keys (4 kt), n = 16 queries of this wave
        f32x4_t s[4] = {};
        #pragma unroll
        for (int k2 = 0; k2 < 2; k2++)
            #pragma unroll
            for (int kt = 0; kt < 4; kt++) {
                const bf16x8_t a = *(const bf16x8_t*)&Ks[buf][ksoff[k2][kt]];
                s[kt] = __builtin_amdgcn_mfma_f32_16x16x32_bf16(
                    a, qf[k2], s[kt], 0, 0, 0);
            }

        // p = exp2(s) (Q pre-scaled by 0.125*log2e); mask only diagonal tile
        const bool edge = (jt == niter - 1);
        #pragma unroll
        for (int kt = 0; kt < 4; kt++) {
            float p[4];
            #pragma unroll
            for (int r = 0; r < 4; r++) {
                float sv = s[kt][r];
                if (edge && (js + kt * 16 + quad * 4 + r > qy)) sv = -3e38f;
                p[r] = exp2f(sv);
            }
            uint2 pk = { pk2bf(p[0], p[1]), pk2bf(p[2], p[3]) };
            *(uint2*)&Ps[w][l16 * 72 + kt * 16 + quad * 4] = pk;
        }
        // no barrier: Ps wave-private, lgkmcnt ordering suffices

        // O += P.V ; l += P.1
        #pragma unroll
        for (int k2 = 0; k2 < 2; k2++) {
            const bf16x8_t ap = *(const bf16x8_t*)&Ps[w][psoff[k2]];
            #pragma unroll
            for (int nt = 0; nt < 4; nt++) {
                const bf16x8_t bv = *(const bf16x8_t*)&Vts[buf][vtoff[k2][nt]];
                o[nt] = __builtin_amdgcn_mfma_f32_16x16x32_bf16(
                    ap, bv, o[nt], 0, 0, 0);
            }
            lacc = __builtin_amdgcn_mfma_f32_16x16x32_bf16(
                ap, ones, lacc, 0, 0, 0);
        }
    }

    // epilogue: C rows = queries (quad*4+r), cols = dh (nt*16+l16)
    #pragma unroll
    for (int r = 0; r < 4; r++) {
        const float inv = 1.0f / lacc[r];
        const int query = qs + w * 16 + quad * 4 + r;
        const int row = b * N_ + query;
        #pragma unroll
        for (int nt = 0; nt < 4; nt++) {
            const int col = h * DH_ + nt * 16 + l16;
            out[(size_t)row * (H_ * DH_) + col] = f2bf(o[nt][r] * inv);
        }
    }
}

// ---------------------------------------------------------------------------
// Host launcher
// ---------------------------------------------------------------------------
extern "C" void kernel_launch(void* const* d_in, const int* in_sizes, int n_in,
                              void* d_out, int out_size, void* d_ws, size_t ws_size,
                              hipStream_t stream) {
    const float* x     = (const float*)d_in[0];
    const float* ln_g  = (const float*)d_in[1];
    const float* ln_b  = (const float*)d_in[2];
    const float* lnc_g = (const float*)d_in[3];
    const float* lnc_b = (const float*)d_in[4];
    const float* Wq    = (const float*)d_in[5];
    const float* Wkv   = (const float*)d_in[6];
    const float* Wo    = (const float*)d_in[7];

    char* ws = (char*)d_ws;
    const size_t MB = 1024 * 1024;
    unsigned short* qkv   = (unsigned short*)(ws + 0 * MB);    // [4096][3072] 24 MB (V region unused)
    unsigned short* vtbuf = (unsigned short*)(ws + 24 * MB);   // tiled V^T      8 MB
    unsigned short* xn    = (unsigned short*)(ws + 32 * MB);   // [4096][1024]  8 MB
    unsigned short* cn    = (unsigned short*)(ws + 40 * MB);   // [4096][1024]  8 MB
    unsigned short* wqkvT = (unsigned short*)(ws + 48 * MB);   // [3072][1024]  6 MB
    unsigned short* woT   = (unsigned short*)(ws + 54 * MB);   // [1024][1024]  2 MB
    unsigned short* ao    = xn;   // reuse: xn dead after QKV GEMM

    // LN (blocks 0..4095) + weight transposes (blocks 4096..8191), one dispatch
    ln_wt_kernel<<<8192, 256, 0, stream>>>(
        x, ln_g, ln_b, lnc_g, lnc_b, Wq, Wkv, Wo, xn, cn, wqkvT, woT);

    // fused Q+KV GEMM; Q pre-scaled; V written tiled-transposed to vtbuf.
    // 768 blocks -> declare 3 blocks/CU so it runs as one full wave.
    gemm_kernel<128, true, true, 3>
        <<<dim3(QKV_N / 128, BN_ROWS / 128), 256, 0, stream>>>(
        xn, cn, wqkvT, qkv, vtbuf, BN_ROWS, QKV_N, D_);

    flash_attn_kernel<<<B_ * H_ * 32, 256, 0, stream>>>(qkv, vtbuf, ao);

    // out = ao @ woT^T (fp32 out); BM=64 -> 512 blocks = 2/CU
    gemm_kernel<64, false, false, 2>
        <<<dim3(D_ / 128, BN_ROWS / 64), 256, 0, stream>>>(
        ao, nullptr, woT, (float*)d_out, nullptr, BN_ROWS, D_, H_ * DH_);
}